// Round 5
// baseline (753.361 us; speedup 1.0000x reference)
//
#include <hip/hip_runtime.h>
#include <hip/hip_bf16.h>

#define VOCAB 500000
#define DD 64

typedef float floatx4 __attribute__((ext_vector_type(4)));

// Phase 1: transpose both weight matrices [64][VOCAB] into fused table
// T[v][0..63] = mean_w[:, v], T[v][64..127] = exp(2*logvar_w[:, v]).
// LDS-tiled 64x64, pad 65 -> 2-way bank aliasing only (free on CDNA4).
// float4 global on both sides. W reads are nontemporal (single-use stream,
// keep L3 free to retain T for phase 2); T stores are cached.
__global__ __launch_bounds__(256) void transpose_exp_kernel(
    const float* __restrict__ mean_w,
    const float* __restrict__ logvar_w,
    float* __restrict__ T)
{
    __shared__ float tm[DD][65];
    __shared__ float tv[DD][65];

    const int t      = threadIdx.x;
    const int lane16 = t & 15;     // 16-lane sub-group id
    const int grp    = t >> 4;     // 0..15 across the block
    const int v0     = blockIdx.x * 64;

    // ---- load: rows of W, coalesced float4 (256B per 16-lane group) ----
#pragma unroll
    for (int rep = 0; rep < 4; ++rep) {
        const int d = rep * 16 + grp;          // 0..63
        const int v = v0 + lane16 * 4;
        if (v < VOCAB) {                       // VOCAB % 4 == 0 -> v<VOCAB implies v+3<VOCAB
            const floatx4 m4 = __builtin_nontemporal_load(
                reinterpret_cast<const floatx4*>(&mean_w  [(size_t)d * VOCAB + v]));
            const floatx4 l4 = __builtin_nontemporal_load(
                reinterpret_cast<const floatx4*>(&logvar_w[(size_t)d * VOCAB + v]));
#pragma unroll
            for (int k = 0; k < 4; ++k) {
                tm[d][lane16 * 4 + k] = m4[k];
                tv[d][lane16 * 4 + k] = __expf(2.0f * l4[k]);
            }
        }
    }
    __syncthreads();

    // ---- store: rows of T, coalesced float4 (256B per 16-lane group) ----
#pragma unroll
    for (int rep = 0; rep < 4; ++rep) {
        const int j = rep * 16 + grp;          // column inside the v-tile
        const int v = v0 + j;
        if (v < VOCAB) {
            floatx4 sm, sv;
#pragma unroll
            for (int k = 0; k < 4; ++k) {
                sm[k] = tm[lane16 * 4 + k][j];
                sv[k] = tv[lane16 * 4 + k][j];
            }
            *reinterpret_cast<floatx4*>(&T[(size_t)v * 128 +      lane16 * 4]) = sm;
            *reinterpret_cast<floatx4*>(&T[(size_t)v * 128 + 64 + lane16 * 4]) = sv;
        }
    }
}

// Phase 2: gather. 16 consecutive lanes serve one lookup: each lane pulls one
// float4 of mean and one float4 of var from the 512B table row (two fully-
// consumed 256B segments -> zero line amplification). Output writes are
// contiguous 4KB per wave; nontemporal so the 512MB output stream doesn't
// evict the L3-resident table. 2048-block grid-stride (G11).
__global__ __launch_bounds__(256) void gather_kernel(
    const int* __restrict__ idx,
    const float* __restrict__ T,
    float* __restrict__ out,
    unsigned N)
{
    const unsigned total4 = N * 16u;                    // float4 slots in mean half
    const floatx4* T4 = reinterpret_cast<const floatx4*>(T);
    floatx4* out4 = reinterpret_cast<floatx4*>(out);

    for (unsigned i = blockIdx.x * 256u + threadIdx.x; i < total4;
         i += gridDim.x * 256u) {
        const unsigned n  = i >> 4;
        const unsigned q  = i & 15u;
        const unsigned id = (unsigned)idx[n];

        const floatx4 m = T4[(size_t)id * 32 + q];
        const floatx4 v = T4[(size_t)id * 32 + 16 + q];

        __builtin_nontemporal_store(m, &out4[i]);
        __builtin_nontemporal_store(v, &out4[(size_t)total4 + i]);
    }
}

// Fallback if ws is too small for the 256MB transposed table: direct gather.
__global__ __launch_bounds__(256) void direct_kernel(
    const int* __restrict__ idx,
    const float* __restrict__ mean_w,
    const float* __restrict__ logvar_w,
    float* __restrict__ out,
    long long total)
{
    for (long long i = (long long)blockIdx.x * 256 + threadIdx.x; i < total;
         i += (long long)gridDim.x * 256) {
        const int n  = (int)(i >> 6);
        const int d  = (int)(i & 63);
        const int id = idx[n];
        const float m  = mean_w  [(size_t)d * VOCAB + id];
        const float lv = logvar_w[(size_t)d * VOCAB + id];
        __builtin_nontemporal_store(m, &out[i]);
        __builtin_nontemporal_store(__expf(2.0f * lv), &out[total + i]);
    }
}

extern "C" void kernel_launch(void* const* d_in, const int* in_sizes, int n_in,
                              void* d_out, int out_size, void* d_ws, size_t ws_size,
                              hipStream_t stream) {
    const int*   idx      = (const int*)  d_in[0];
    const float* mean_w   = (const float*)d_in[1];
    const float* logvar_w = (const float*)d_in[2];
    float*       out      = (float*)      d_out;
    const unsigned N      = (unsigned)in_sizes[0];

    const size_t t_bytes = (size_t)VOCAB * 128 * sizeof(float);   // 256 MB
    if (ws_size >= t_bytes) {
        float* T = (float*)d_ws;
        transpose_exp_kernel<<<(VOCAB + 63) / 64, 256, 0, stream>>>(mean_w, logvar_w, T);
        gather_kernel<<<2048, 256, 0, stream>>>(idx, T, out, N);
    } else {
        const long long total = (long long)N * 64;
        direct_kernel<<<2048, 256, 0, stream>>>(idx, mean_w, logvar_w, out, total);
    }
}